// Round 5
// baseline (130.889 us; speedup 1.0000x reference)
//
#include <hip/hip_runtime.h>
#include <math.h>

#define D 256
#define K2 512          // 2*D
#define BATCH 1024      // n2
#define N1 11264        // n1 = B*(1+10)
#define S0 25
#define S1 10
#define NFLOAT4 6400000 // 100000*256/4

typedef __bf16 bf16x8 __attribute__((ext_vector_type(8)));
typedef __bf16 bf16x4 __attribute__((ext_vector_type(4)));
typedef float  f32x4  __attribute__((ext_vector_type(4)));

// ---------------------------------------------------------------------------
// convert_all: features (100MB fp32 -> 50MB bf16) + W0/W1 -> bf16. Streaming.
// ---------------------------------------------------------------------------
__global__ __launch_bounds__(256) void convert_all(
        const float* __restrict__ feat, const float* __restrict__ W0,
        const float* __restrict__ W1, __bf16* __restrict__ featb,
        __bf16* __restrict__ Wb0, __bf16* __restrict__ Wb1) {
    const int total = NFLOAT4 + 65536;
    for (int i = blockIdx.x * 256 + threadIdx.x; i < total; i += gridDim.x * 256) {
        const float* src; __bf16* dst; int j;
        if (i < NFLOAT4)              { src = feat; dst = featb; j = i; }
        else if (i < NFLOAT4 + 32768) { src = W0;   dst = Wb0;   j = i - NFLOAT4; }
        else                          { src = W1;   dst = Wb1;   j = i - NFLOAT4 - 32768; }
        float4 v = ((const float4*)src)[j];
        bf16x4 o = { (__bf16)v.x, (__bf16)v.y, (__bf16)v.z, (__bf16)v.w };
        *(bf16x4*)(dst + (size_t)j * 4) = o;
    }
}

// small-ws fallback: convert only W0/W1
__global__ __launch_bounds__(256) void convert_w(
        const float* __restrict__ W0, const float* __restrict__ W1,
        __bf16* __restrict__ Wb0, __bf16* __restrict__ Wb1) {
    int i = blockIdx.x * 256 + threadIdx.x;   // 65536 threads
    const float* src = (i < 32768) ? W0 : W1;
    __bf16* dst = (i < 32768) ? Wb0 : Wb1;
    int j = i & 32767;
    float4 v = ((const float4*)src)[j];
    bf16x4 o = { (__bf16)v.x, (__bf16)v.y, (__bf16)v.z, (__bf16)v.w };
    *(bf16x4*)(dst + (size_t)j * 4) = o;
}

// ---------------------------------------------------------------------------
// gather_x0_bf16: one wave per node; lane owns dims [4l,4l+4) (bf16x4 = 8B).
// All 26 row-loads batched into registers BEFORE accumulation -> max MLP.
// Row = 512B contiguous per load instruction. Indices are wave-uniform (SGPR).
// ---------------------------------------------------------------------------
__global__ __launch_bounds__(256) void gather_x0_bf16(
        const __bf16* __restrict__ featb, const int* __restrict__ nodes2,
        const int* __restrict__ neigh2, const int* __restrict__ neigh1,
        __bf16* __restrict__ X0) {
    const int wave = (blockIdx.x * 256 + threadIdx.x) >> 6;
    const int lane = threadIdx.x & 63;
    const int self_idx = (wave < BATCH) ? nodes2[wave] : neigh2[wave - BATCH];
    const int* nb = neigh1 + (size_t)wave * S0;
    int idx[S0];
#pragma unroll
    for (int j = 0; j < S0; ++j) idx[j] = nb[j];
    bf16x4 selfv = *(const bf16x4*)(featb + (size_t)self_idx * D + lane * 4);
    bf16x4 v[S0];
#pragma unroll
    for (int j = 0; j < S0; ++j)
        v[j] = *(const bf16x4*)(featb + (size_t)idx[j] * D + lane * 4);
    float a0 = 0.f, a1 = 0.f, a2 = 0.f, a3 = 0.f;
#pragma unroll
    for (int j = 0; j < S0; ++j) {
        a0 += (float)v[j][0]; a1 += (float)v[j][1];
        a2 += (float)v[j][2]; a3 += (float)v[j][3];
    }
    const float s = 1.0f / (float)S0;
    bf16x4 av = { (__bf16)(a0 * s), (__bf16)(a1 * s),
                  (__bf16)(a2 * s), (__bf16)(a3 * s) };
    __bf16* xr = X0 + (size_t)wave * K2;
    *(bf16x4*)(xr + lane * 4) = selfv;
    *(bf16x4*)(xr + 256 + lane * 4) = av;
}

// fp32-source variant (small-ws fallback), same structure, float4 per lane.
__global__ __launch_bounds__(256) void gather_x0_f32(
        const float* __restrict__ feat, const int* __restrict__ nodes2,
        const int* __restrict__ neigh2, const int* __restrict__ neigh1,
        __bf16* __restrict__ X0) {
    const int wave = (blockIdx.x * 256 + threadIdx.x) >> 6;
    const int lane = threadIdx.x & 63;
    const int self_idx = (wave < BATCH) ? nodes2[wave] : neigh2[wave - BATCH];
    const int* nb = neigh1 + (size_t)wave * S0;
    int idx[S0];
#pragma unroll
    for (int j = 0; j < S0; ++j) idx[j] = nb[j];
    float4 sv = ((const float4*)(feat + (size_t)self_idx * D))[lane];
    float4 v[S0];
#pragma unroll
    for (int j = 0; j < S0; ++j)
        v[j] = ((const float4*)(feat + (size_t)idx[j] * D))[lane];
    float4 acc = make_float4(0.f, 0.f, 0.f, 0.f);
#pragma unroll
    for (int j = 0; j < S0; ++j) {
        acc.x += v[j].x; acc.y += v[j].y; acc.z += v[j].z; acc.w += v[j].w;
    }
    const float s = 1.0f / (float)S0;
    bf16x4 svb = { (__bf16)sv.x, (__bf16)sv.y, (__bf16)sv.z, (__bf16)sv.w };
    bf16x4 av = { (__bf16)(acc.x * s), (__bf16)(acc.y * s),
                  (__bf16)(acc.z * s), (__bf16)(acc.w * s) };
    __bf16* xr = X0 + (size_t)wave * K2;
    *(bf16x4*)(xr + lane * 4) = svb;
    *(bf16x4*)(xr + 256 + lane * 4) = av;
}

// ---------------------------------------------------------------------------
// MFMA GEMM: Out[M][256] = l2norm_rows(relu(A[M][512] @ W[256][512]^T + bias))
// (proven round-2/3 template; tile16 LDS layout, reg-prefetch pipeline)
// ---------------------------------------------------------------------------
template <int RB, typename OutT>
__global__ __launch_bounds__(256, 2) void gemm_bt_relu_norm(
        const __bf16* __restrict__ A, const __bf16* __restrict__ W,
        const float* __restrict__ bias, OutT* __restrict__ Out) {
    constexpr int RF = RB / 16;
    constexpr int NA = RB * 8;
    constexpr int ASTG = (NA + 255) / 256;
    __shared__ __bf16 As[RB * 64];
    __shared__ __bf16 Bs[256 * 64];
    __shared__ float ssLDS[4][RB];
    __shared__ float invLDS[RB];

    const int tid = threadIdx.x;
    const int row0 = blockIdx.x * RB;
    const int lane = tid & 63;
    const int w = tid >> 6;
    const int rl = lane & 15;
    const int g = lane >> 4;

    uint4 ra[ASTG], rb[8];
#pragma unroll
    for (int s = 0; s < ASTG; ++s) {
        int i = tid + s * 256;
        if (i < NA) {
            int rg = i >> 7, kc = (i >> 4) & 7, lo = i & 15;
            ra[s] = *(const uint4*)(A + (size_t)(row0 + rg * 16 + lo) * K2 + kc * 8);
        }
    }
#pragma unroll
    for (int s = 0; s < 8; ++s) {
        int i = tid + s * 256;
        int cg = i >> 7, kc = (i >> 4) & 7, lo = i & 15;
        rb[s] = *(const uint4*)(W + (size_t)(cg * 16 + lo) * K2 + kc * 8);
    }

    f32x4 acc[RF][4];
#pragma unroll
    for (int rf = 0; rf < RF; ++rf)
#pragma unroll
        for (int nf = 0; nf < 4; ++nf) acc[rf][nf] = (f32x4){0.f, 0.f, 0.f, 0.f};

    for (int k0 = 0; k0 < K2; k0 += 64) {
#pragma unroll
        for (int s = 0; s < ASTG; ++s) {
            int i = tid + s * 256;
            if (i < NA) *(uint4*)(As + (size_t)i * 8) = ra[s];
        }
#pragma unroll
        for (int s = 0; s < 8; ++s) {
            int i = tid + s * 256;
            *(uint4*)(Bs + (size_t)i * 8) = rb[s];
        }
        __syncthreads();
        if (k0 + 64 < K2) {
            int kn = k0 + 64;
#pragma unroll
            for (int s = 0; s < ASTG; ++s) {
                int i = tid + s * 256;
                if (i < NA) {
                    int rg = i >> 7, kc = (i >> 4) & 7, lo = i & 15;
                    ra[s] = *(const uint4*)(A + (size_t)(row0 + rg * 16 + lo) * K2 + kn + kc * 8);
                }
            }
#pragma unroll
            for (int s = 0; s < 8; ++s) {
                int i = tid + s * 256;
                int cg = i >> 7, kc = (i >> 4) & 7, lo = i & 15;
                rb[s] = *(const uint4*)(W + (size_t)(cg * 16 + lo) * K2 + kn + kc * 8);
            }
        }
#pragma unroll
        for (int kf = 0; kf < 2; ++kf) {
            const int kc = kf * 4 + g;
            bf16x8 af[RF], bfr[4];
#pragma unroll
            for (int rf = 0; rf < RF; ++rf)
                af[rf] = *(const bf16x8*)(As + ((size_t)(rf * 8 + kc) * 16 + rl) * 8);
#pragma unroll
            for (int nf = 0; nf < 4; ++nf)
                bfr[nf] = *(const bf16x8*)(Bs + ((size_t)((w * 4 + nf) * 8 + kc) * 16 + rl) * 8);
#pragma unroll
            for (int rf = 0; rf < RF; ++rf)
#pragma unroll
                for (int nf = 0; nf < 4; ++nf)
                    acc[rf][nf] = __builtin_amdgcn_mfma_f32_16x16x32_bf16(
                        af[rf], bfr[nf], acc[rf][nf], 0, 0, 0);
        }
        __syncthreads();
    }

    float bv[4];
#pragma unroll
    for (int nf = 0; nf < 4; ++nf) bv[nf] = bias[w * 64 + nf * 16 + rl];

#pragma unroll
    for (int rf = 0; rf < RF; ++rf) {
        float ss0 = 0.f, ss1 = 0.f, ss2 = 0.f, ss3 = 0.f;
#pragma unroll
        for (int nf = 0; nf < 4; ++nf) {
            float v0 = fmaxf(acc[rf][nf][0] + bv[nf], 0.f);
            float v1 = fmaxf(acc[rf][nf][1] + bv[nf], 0.f);
            float v2 = fmaxf(acc[rf][nf][2] + bv[nf], 0.f);
            float v3 = fmaxf(acc[rf][nf][3] + bv[nf], 0.f);
            acc[rf][nf][0] = v0; acc[rf][nf][1] = v1;
            acc[rf][nf][2] = v2; acc[rf][nf][3] = v3;
            ss0 += v0 * v0; ss1 += v1 * v1; ss2 += v2 * v2; ss3 += v3 * v3;
        }
#pragma unroll
        for (int m = 1; m < 16; m <<= 1) {
            ss0 += __shfl_xor(ss0, m);
            ss1 += __shfl_xor(ss1, m);
            ss2 += __shfl_xor(ss2, m);
            ss3 += __shfl_xor(ss3, m);
        }
        float ssv = (rl == 0) ? ss0 : (rl == 1) ? ss1 : (rl == 2) ? ss2 : ss3;
        if (rl < 4) ssLDS[w][rf * 16 + g * 4 + rl] = ssv;
    }
    __syncthreads();
    if (tid < RB) {
        float t = ssLDS[0][tid] + ssLDS[1][tid] + ssLDS[2][tid] + ssLDS[3][tid];
        invLDS[tid] = (t > 0.f) ? rsqrtf(t) : 1.0f;
    }
    __syncthreads();
#pragma unroll
    for (int rf = 0; rf < RF; ++rf)
#pragma unroll
        for (int j = 0; j < 4; ++j) {
            const int row = rf * 16 + g * 4 + j;
            const float inv = invLDS[row];
#pragma unroll
            for (int nf = 0; nf < 4; ++nf)
                Out[(size_t)(row0 + row) * D + w * 64 + nf * 16 + rl] =
                    (OutT)(acc[rf][nf][j] * inv);
        }
}

// ---------------------------------------------------------------------------
// fused_layer1: Out[1024][256] = l2norm(relu(X1 @ W1^T + b1)); X1 row i =
// [h1[i] | mean_j h1[1024+i*10+j]] built on the fly. BOTH A (incl. the 10
// agg row loads) and B are prefetched one k-iter ahead (T14) so the scattered
// agg loads hide under MFMA instead of stalling each iteration.
// ---------------------------------------------------------------------------
__global__ __launch_bounds__(256, 2) void fused_layer1(
        const __bf16* __restrict__ h1, const __bf16* __restrict__ Wb,
        const float* __restrict__ b1, float* __restrict__ Out) {
    constexpr int RB = 32;
    __shared__ __bf16 As[RB * 64];
    __shared__ __bf16 Bs[256 * 64];
    __shared__ float ssLDS[4][RB];
    __shared__ float invLDS[RB];

    const int tid = threadIdx.x;
    const int row0 = blockIdx.x * RB;
    const int lane = tid & 63;
    const int w = tid >> 6;
    const int rl = lane & 15;
    const int g = lane >> 4;
    const int rg = tid >> 7, kc8 = (tid >> 4) & 7, lo = tid & 15;
    const int grow = row0 + rg * 16 + lo;

    bf16x8 areg[S1];
    uint4 breg[8];
    int acur = 1;   // number of valid areg entries (1 = self phase, 10 = agg)

    // prologue (k0 = 0): self phase
    areg[0] = *(const bf16x8*)(h1 + (size_t)grow * D + kc8 * 8);
#pragma unroll
    for (int s = 0; s < 8; ++s) {
        int i = tid + s * 256;
        int cg = i >> 7, kc = (i >> 4) & 7, blo = i & 15;
        breg[s] = *(const uint4*)(Wb + (size_t)(cg * 16 + blo) * K2 + kc * 8);
    }

    f32x4 acc[2][4];
#pragma unroll
    for (int rf = 0; rf < 2; ++rf)
#pragma unroll
        for (int nf = 0; nf < 4; ++nf) acc[rf][nf] = (f32x4){0.f, 0.f, 0.f, 0.f};

    for (int k0 = 0; k0 < K2; k0 += 64) {
        // ---- write staged A ----
        bf16x8 av;
        if (acur == 1) {
            av = areg[0];
        } else {
            float f[8];
#pragma unroll
            for (int e = 0; e < 8; ++e) f[e] = 0.f;
#pragma unroll
            for (int j = 0; j < S1; ++j)
#pragma unroll
                for (int e = 0; e < 8; ++e) f[e] += (float)areg[j][e];
#pragma unroll
            for (int e = 0; e < 8; ++e) av[e] = (__bf16)(f[e] * 0.1f);
        }
        *(bf16x8*)(As + (size_t)tid * 8) = av;
        // ---- write staged B ----
#pragma unroll
        for (int s = 0; s < 8; ++s)
            *(uint4*)(Bs + (size_t)(tid + s * 256) * 8) = breg[s];
        __syncthreads();
        // ---- prefetch next k-tile ----
        if (k0 + 64 < K2) {
            const int kn = k0 + 64;
            if (kn < 256) {
                areg[0] = *(const bf16x8*)(h1 + (size_t)grow * D + kn + kc8 * 8);
                acur = 1;
            } else {
                const __bf16* base = h1 + (size_t)(BATCH + grow * S1) * D + (kn - 256) + kc8 * 8;
#pragma unroll
                for (int j = 0; j < S1; ++j)
                    areg[j] = *(const bf16x8*)(base + (size_t)j * D);
                acur = S1;
            }
#pragma unroll
            for (int s = 0; s < 8; ++s) {
                int i = tid + s * 256;
                int cg = i >> 7, kc = (i >> 4) & 7, blo = i & 15;
                breg[s] = *(const uint4*)(Wb + (size_t)(cg * 16 + blo) * K2 + kn + kc * 8);
            }
        }
        // ---- MFMA ----
#pragma unroll
        for (int kf = 0; kf < 2; ++kf) {
            const int kc = kf * 4 + g;
            bf16x8 af[2], bfr[4];
#pragma unroll
            for (int rf = 0; rf < 2; ++rf)
                af[rf] = *(const bf16x8*)(As + ((size_t)(rf * 8 + kc) * 16 + rl) * 8);
#pragma unroll
            for (int nf = 0; nf < 4; ++nf)
                bfr[nf] = *(const bf16x8*)(Bs + ((size_t)((w * 4 + nf) * 8 + kc) * 16 + rl) * 8);
#pragma unroll
            for (int rf = 0; rf < 2; ++rf)
#pragma unroll
                for (int nf = 0; nf < 4; ++nf)
                    acc[rf][nf] = __builtin_amdgcn_mfma_f32_16x16x32_bf16(
                        af[rf], bfr[nf], acc[rf][nf], 0, 0, 0);
        }
        __syncthreads();
    }

    float bv[4];
#pragma unroll
    for (int nf = 0; nf < 4; ++nf) bv[nf] = b1[w * 64 + nf * 16 + rl];

#pragma unroll
    for (int rf = 0; rf < 2; ++rf) {
        float ss0 = 0.f, ss1 = 0.f, ss2 = 0.f, ss3 = 0.f;
#pragma unroll
        for (int nf = 0; nf < 4; ++nf) {
            float v0 = fmaxf(acc[rf][nf][0] + bv[nf], 0.f);
            float v1 = fmaxf(acc[rf][nf][1] + bv[nf], 0.f);
            float v2 = fmaxf(acc[rf][nf][2] + bv[nf], 0.f);
            float v3 = fmaxf(acc[rf][nf][3] + bv[nf], 0.f);
            acc[rf][nf][0] = v0; acc[rf][nf][1] = v1;
            acc[rf][nf][2] = v2; acc[rf][nf][3] = v3;
            ss0 += v0 * v0; ss1 += v1 * v1; ss2 += v2 * v2; ss3 += v3 * v3;
        }
#pragma unroll
        for (int m = 1; m < 16; m <<= 1) {
            ss0 += __shfl_xor(ss0, m);
            ss1 += __shfl_xor(ss1, m);
            ss2 += __shfl_xor(ss2, m);
            ss3 += __shfl_xor(ss3, m);
        }
        float ssv = (rl == 0) ? ss0 : (rl == 1) ? ss1 : (rl == 2) ? ss2 : ss3;
        if (rl < 4) ssLDS[w][rf * 16 + g * 4 + rl] = ssv;
    }
    __syncthreads();
    if (tid < RB) {
        float t = ssLDS[0][tid] + ssLDS[1][tid] + ssLDS[2][tid] + ssLDS[3][tid];
        invLDS[tid] = (t > 0.f) ? rsqrtf(t) : 1.0f;
    }
    __syncthreads();
#pragma unroll
    for (int rf = 0; rf < 2; ++rf)
#pragma unroll
        for (int j = 0; j < 4; ++j) {
            const int row = rf * 16 + g * 4 + j;
            const float inv = invLDS[row];
#pragma unroll
            for (int nf = 0; nf < 4; ++nf)
                Out[(size_t)(row0 + row) * D + w * 64 + nf * 16 + rl] = acc[rf][nf][j] * inv;
        }
}

// ---------------------------------------------------------------------------
extern "C" void kernel_launch(void* const* d_in, const int* in_sizes, int n_in,
                              void* d_out, int out_size, void* d_ws, size_t ws_size,
                              hipStream_t stream) {
    const float* features = (const float*)d_in[0];
    const float* W0       = (const float*)d_in[1];
    const float* b0       = (const float*)d_in[2];
    const float* W1       = (const float*)d_in[3];
    const float* b1       = (const float*)d_in[4];
    const int*   nodes2   = (const int*)d_in[5];
    const int*   neigh2   = (const int*)d_in[6];
    const int*   neigh1   = (const int*)d_in[7];
    float* out = (float*)d_out;

    const size_t featb_bytes = (size_t)100000 * 256 * 2;            // 51.2 MB
    const size_t tail_bytes = 524288 + 11534336 + 5767168;          // Wb + X0b + h1b
    const bool big = ws_size >= featb_bytes + tail_bytes;

    char* ws = (char*)d_ws;
    __bf16* featb = (__bf16*)ws;
    char* p = ws + (big ? featb_bytes : 0);
    __bf16* Wb0 = (__bf16*)p;
    __bf16* Wb1 = (__bf16*)(p + 262144);
    __bf16* X0b = (__bf16*)(p + 524288);
    __bf16* h1b = (__bf16*)(p + 524288 + 11534336);

    if (big) {
        convert_all<<<2048, 256, 0, stream>>>(features, W0, W1, featb, Wb0, Wb1);
        gather_x0_bf16<<<N1 / 4, 256, 0, stream>>>(featb, nodes2, neigh2, neigh1, X0b);
    } else {
        convert_w<<<256, 256, 0, stream>>>(W0, W1, Wb0, Wb1);
        gather_x0_f32<<<N1 / 4, 256, 0, stream>>>(features, nodes2, neigh2, neigh1, X0b);
    }

    gemm_bt_relu_norm<64, __bf16><<<N1 / 64, 256, 0, stream>>>(X0b, Wb0, b0, h1b);
    fused_layer1<<<BATCH / 32, 256, 0, stream>>>(h1b, Wb1, b1, out);
}